// Round 9
// baseline (326.417 us; speedup 1.0000x reference)
//
#include <hip/hip_runtime.h>
#include <hip/hip_bf16.h>

#define N_NODES 200000
#define KDIM 27
#define C_IN 32
#define C_OUT 32
#define NPART 4
#define PSIZE 50000              // N_NODES/NPART; 3.2 MB bf16 per partition
#define TILES 4                  // tiles (128 nodes each) per block
#define SEGS (TILES * KDIM)      // 108 stages per pass; 108 % PF == 0
#define PF 6                     // frag ring depth; 24 loads in flight

typedef __bf16 bf16x8 __attribute__((ext_vector_type(8)));
typedef float floatx4 __attribute__((ext_vector_type(4)));
typedef float float4_t __attribute__((ext_vector_type(4)));

__device__ __forceinline__ void load_frag16(bf16x8& dst, const __bf16* addr) {
    asm volatile("global_load_dwordx4 %0, %1, off" : "=v"(dst) : "v"(addr));
}

// ---------------- Kernel 1: fused convert (fp32->bf16 + sentinel) + pack ---
__global__ __launch_bounds__(256) void prep_kernel(
    const float* __restrict__ data, const float* __restrict__ w,
    __bf16* __restrict__ data_bf, __bf16* __restrict__ wpack) {
    const int b = blockIdx.x;
    const int tid = threadIdx.x;
    if (b < 3125) {                       // convert: 3125*256*8 = 6.4M elems
        int i = b * 256 + tid;
        const float4_t* s = (const float4_t*)data;
        float4_t v0 = __builtin_nontemporal_load(&s[2 * i]);
        float4_t v1 = __builtin_nontemporal_load(&s[2 * i + 1]);
        bf16x8 o;
        o[0] = (__bf16)v0[0]; o[1] = (__bf16)v0[1];
        o[2] = (__bf16)v0[2]; o[3] = (__bf16)v0[3];
        o[4] = (__bf16)v1[0]; o[5] = (__bf16)v1[1];
        o[6] = (__bf16)v1[2]; o[7] = (__bf16)v1[3];
        ((bf16x8*)data_bf)[i] = o;
        if (b == 0 && tid < 4) {          // zero sentinel node N_NODES
            bf16x8 z;
#pragma unroll
            for (int t = 0; t < 8; ++t) z[t] = (__bf16)0.0f;
            ((bf16x8*)data_bf)[N_NODES * 4 + tid] = z;
        }
    } else {                              // pack weights: 108 blocks
        int id = (b - 3125) * 256 + tid;
        int j = id & 7;
        int l = (id >> 3) & 63;
        int t = (id >> 9) & 1;
        int kk = id >> 10;
        int c = ((l >> 4) << 3) + j;
        int o = t * 16 + (l & 15);
        wpack[id] = (__bf16)w[(kk * C_IN + c) * C_OUT + o];
    }
}

// ---------------- Kernel 2: persistent soft-synced partition gather-GEMM ---
// dur = (FETCH+WRITE)/3.2 TB/s in every measured variant -> traffic-bound;
// only lever is FETCH reduction via partition residency. R7 failed because
// 1563 churning blocks start-stagger across the whole kernel; R8's coop
// launch never executed (zero output = launch refused). Here: 512 blocks =
// exactly 2/CU (LDS 2x55.3KB, <=256 VGPR at (256,2), 8 waves/CU) -> the
// whole grid is CO-RESIDENT and starts together; identical per-pass work
// keeps passes aligned within ~10% drift, no grid barrier needed. Phantom
// blocks (base >= N) run on the L1-hot sentinel and don't pollute L2.
// Out-of-partition taps -> zero sentinel (exact: fp32 acc + 0.0).

#define MFMA4(S, CT)                                                            \
    acc00[CT] = __builtin_amdgcn_mfma_f32_16x16x32_bf16(a0b[S], b0b[S], acc00[CT], 0, 0, 0); \
    acc01[CT] = __builtin_amdgcn_mfma_f32_16x16x32_bf16(a0b[S], b1b[S], acc01[CT], 0, 0, 0); \
    acc10[CT] = __builtin_amdgcn_mfma_f32_16x16x32_bf16(a1b[S], b0b[S], acc10[CT], 0, 0, 0); \
    acc11[CT] = __builtin_amdgcn_mfma_f32_16x16x32_bf16(a1b[S], b1b[S], acc11[CT], 0, 0, 0);

#define STAGE(J)                                                                \
    {                                                                           \
        asm volatile("s_waitcnt vmcnt(20)" ::: "memory");                       \
        __builtin_amdgcn_sched_barrier(0);                                      \
        constexpr int s_  = (J) % PF;                                           \
        constexpr int ct_ = (J) / KDIM;            /* consume tile for acc */   \
        MFMA4(s_, ct_)                                                          \
        {                                                                       \
            constexpr int T_  = (J) + PF;          /* issue target stage  */    \
            constexpr int kT_ = T_ % KDIM;                                      \
            const int lo_ = (T_ < SEGS) ? lo_cur : lo_next;                     \
            int raw0_ = rp0[(J) % 3];                                           \
            int raw1_ = rp1[(J) % 3];                                           \
            unsigned u0_ = ((unsigned)raw0_ - (unsigned)lo_ < (unsigned)PSIZE)  \
                               ? (unsigned)raw0_ : (unsigned)N_NODES;           \
            unsigned u1_ = ((unsigned)raw1_ - (unsigned)lo_ < (unsigned)PSIZE)  \
                               ? (unsigned)raw1_ : (unsigned)N_NODES;           \
            load_frag16(a0b[s_], dch + ((size_t)u0_ << 5));                     \
            load_frag16(a1b[s_], dch + ((size_t)u1_ << 5));                     \
            load_frag16(b0b[s_], wlane + kT_ * 1024);                           \
            load_frag16(b1b[s_], wlane + kT_ * 1024 + 512);                     \
        }                                                                       \
        {                                                                       \
            constexpr int T2_ = ((J) + 8) % SEGS;  /* idx for stage J+2 use */  \
            constexpr int t2_ = T2_ / KDIM, k2_ = T2_ % KDIM;                   \
            rp0[((J) + 2) % 3] = nlds[t2_ * 3456 + rA0 + k2_];                  \
            rp1[((J) + 2) % 3] = nlds[t2_ * 3456 + rA0 + 432 + k2_];            \
        }                                                                       \
    }

#define S9(a) STAGE(a) STAGE((a)+1) STAGE((a)+2) STAGE((a)+3) STAGE((a)+4) \
              STAGE((a)+5) STAGE((a)+6) STAGE((a)+7) STAGE((a)+8)

#define PRIME(T)                                                                \
    {                                                                           \
        int q0 = nlds[rA0 + (T)];                                               \
        int q1 = nlds[rA0 + 432 + (T)];                                         \
        unsigned u0_ = ((unsigned)q0 < (unsigned)PSIZE) ? (unsigned)q0          \
                                                        : (unsigned)N_NODES;    \
        unsigned u1_ = ((unsigned)q1 < (unsigned)PSIZE) ? (unsigned)q1          \
                                                        : (unsigned)N_NODES;    \
        load_frag16(a0b[(T)], dch + ((size_t)u0_ << 5));                        \
        load_frag16(a1b[(T)], dch + ((size_t)u1_ << 5));                        \
        load_frag16(b0b[(T)], wlane + (T) * 1024);                              \
        load_frag16(b1b[(T)], wlane + (T) * 1024 + 512);                        \
    }

__global__ __launch_bounds__(256, 2) void octconv_main_kernel(
    const int* __restrict__ neigh, const __bf16* __restrict__ data_bf,
    const __bf16* __restrict__ wpack, float* __restrict__ out) {
    __shared__ int nlds[TILES * 128 * KDIM];   // 55296 B: 4 tile slabs

    const int tid  = threadIdx.x;
    const int wave = tid >> 6;
    const int lane = tid & 63;
    const int r16  = lane & 15;
    const int half = lane >> 4;
    const int cb   = half << 3;

    // stage this block's 4 tiles' neigh -> LDS once (contiguous, coalesced)
    {
        const long long gbase = (long long)blockIdx.x * (TILES * 128 * KDIM);
        const long long gmax  = (long long)N_NODES * KDIM;
#pragma unroll 1
        for (int i = tid; i < TILES * 128 * KDIM; i += 256) {
            long long gg = gbase + i;
            nlds[i] = (gg < gmax) ? __builtin_nontemporal_load(&neigh[gg]) : -1;
        }
    }
    __syncthreads();

    const int rA0 = (wave * 32 + r16) * KDIM;    // row base within a tile slab
    const __bf16* dch   = data_bf + cb;
    const __bf16* wlane = wpack + (size_t)lane * 8;

    floatx4 acc00[TILES], acc01[TILES], acc10[TILES], acc11[TILES];
#pragma unroll
    for (int t = 0; t < TILES; ++t) {
        acc00[t] = floatx4{0.f, 0.f, 0.f, 0.f};
        acc01[t] = floatx4{0.f, 0.f, 0.f, 0.f};
        acc10[t] = floatx4{0.f, 0.f, 0.f, 0.f};
        acc11[t] = floatx4{0.f, 0.f, 0.f, 0.f};
    }

    bf16x8 a0b[PF], a1b[PF], b0b[PF], b1b[PF];   // asm-pinned frag ring
    int rp0[3], rp1[3];                          // idx ring, 2-stage lead

    // prologue (pass 0, lo=0): issue targets 0..5 (tile 0), prime idx ring
    PRIME(0) PRIME(1) PRIME(2) PRIME(3) PRIME(4) PRIME(5)
    rp0[0] = nlds[rA0 + 6]; rp1[0] = nlds[rA0 + 432 + 6];   // for target 6
    rp0[1] = nlds[rA0 + 7]; rp1[1] = nlds[rA0 + 432 + 7];   // for target 7

    int lo_cur = 0, lo_next = PSIZE;
#pragma unroll 1
    for (int p = 0; p < NPART; ++p) {
        S9(0)  S9(9)  S9(18) S9(27) S9(36) S9(45)
        S9(54) S9(63) S9(72) S9(81) S9(90) S9(99)
        lo_cur += PSIZE;
        lo_next += PSIZE;
    }

    asm volatile("s_waitcnt vmcnt(0)" ::: "memory");  // drain phantom issues
    __builtin_amdgcn_sched_barrier(0);

#pragma unroll
    for (int t = 0; t < TILES; ++t) {
        const int node_base = (blockIdx.x * TILES + t) * 128 + wave * 32;
#pragma unroll
        for (int r = 0; r < 4; ++r) {
            int n0 = node_base + half * 4 + r;
            int n1 = n0 + 16;
            if (n0 < N_NODES) {
                __builtin_nontemporal_store(acc00[t][r], &out[n0 * C_OUT + r16]);
                __builtin_nontemporal_store(acc01[t][r], &out[n0 * C_OUT + 16 + r16]);
            }
            if (n1 < N_NODES) {
                __builtin_nontemporal_store(acc10[t][r], &out[n1 * C_OUT + r16]);
                __builtin_nontemporal_store(acc11[t][r], &out[n1 * C_OUT + 16 + r16]);
            }
        }
    }
}

extern "C" void kernel_launch(void* const* d_in, const int* in_sizes, int n_in,
                              void* d_out, int out_size, void* d_ws, size_t ws_size,
                              hipStream_t stream) {
    const float* data    = (const float*)d_in[0];   // [N, C_IN] fp32
    const float* weights = (const float*)d_in[1];   // [K, C_IN, C_OUT] fp32
    const int*   neigh   = (const int*)d_in[2];     // [N, K] int32
    float*       out     = (float*)d_out;           // [N, C_OUT] fp32

    __bf16* data_bf = (__bf16*)d_ws;
    __bf16* wpack   = (__bf16*)((char*)d_ws + (size_t)(N_NODES + 1) * C_IN * sizeof(__bf16));

    // 1) fused convert + sentinel + weight pack
    hipLaunchKernelGGL(prep_kernel, dim3(3125 + 108), dim3(256), 0, stream,
                       data, weights, data_bf, wpack);

    // 2) persistent soft-synced partitioned gather-GEMM: 512 blocks (2/CU,
    //    fully co-resident, regular launch — no cooperative machinery)
    hipLaunchKernelGGL(octconv_main_kernel, dim3(512), dim3(256), 0, stream,
                       neigh, data_bf, wpack, out);
}

// Round 10
// 235.709 us; speedup vs baseline: 1.3848x; 1.3848x over previous
//
#include <hip/hip_runtime.h>
#include <hip/hip_bf16.h>

#define N_NODES 200000
#define KDIM 27
#define C_IN 32
#define C_OUT 32
#define NPART 4
#define PSIZE 50000              // N_NODES/NPART; 3.2 MB bf16 per partition
#define TILES 4                  // tiles (128 nodes each) per block
#define SEGS (TILES * KDIM)      // 108 stages per pass; 108 % PF == 0
#define PF 4                     // frag ring depth: 64 arch VGPRs (fits 128 cap)

typedef __bf16 bf16x8 __attribute__((ext_vector_type(8)));
typedef float floatx4 __attribute__((ext_vector_type(4)));
typedef float float4_t __attribute__((ext_vector_type(4)));

__device__ __forceinline__ void load_frag16(bf16x8& dst, const __bf16* addr) {
    asm volatile("global_load_dwordx4 %0, %1, off" : "=v"(dst) : "v"(addr));
}

// ---------------- Kernel 1: fused convert (fp32->bf16 + sentinel) + pack ---
__global__ __launch_bounds__(256) void prep_kernel(
    const float* __restrict__ data, const float* __restrict__ w,
    __bf16* __restrict__ data_bf, __bf16* __restrict__ wpack) {
    const int b = blockIdx.x;
    const int tid = threadIdx.x;
    if (b < 3125) {                       // convert: 3125*256*8 = 6.4M elems
        int i = b * 256 + tid;
        const float4_t* s = (const float4_t*)data;
        float4_t v0 = __builtin_nontemporal_load(&s[2 * i]);
        float4_t v1 = __builtin_nontemporal_load(&s[2 * i + 1]);
        bf16x8 o;
        o[0] = (__bf16)v0[0]; o[1] = (__bf16)v0[1];
        o[2] = (__bf16)v0[2]; o[3] = (__bf16)v0[3];
        o[4] = (__bf16)v1[0]; o[5] = (__bf16)v1[1];
        o[6] = (__bf16)v1[2]; o[7] = (__bf16)v1[3];
        ((bf16x8*)data_bf)[i] = o;
        if (b == 0 && tid < 4) {          // zero sentinel node N_NODES
            bf16x8 z;
#pragma unroll
            for (int t = 0; t < 8; ++t) z[t] = (__bf16)0.0f;
            ((bf16x8*)data_bf)[N_NODES * 4 + tid] = z;
        }
    } else {                              // pack weights: 108 blocks
        int id = (b - 3125) * 256 + tid;
        int j = id & 7;
        int l = (id >> 3) & 63;
        int t = (id >> 9) & 1;
        int kk = id >> 10;
        int c = ((l >> 4) << 3) + j;
        int o = t * 16 + (l & 15);
        wpack[id] = (__bf16)w[(kk * C_IN + c) * C_OUT + o];
    }
}

// ---------------- Kernel 2: persistent soft-synced partition gather-GEMM ---
// Traffic-bound (dur = bytes/3.2 TB/s in every clean variant). 512 blocks =
// exactly 2/CU co-resident (LDS 2x55.3 KB, (256,2)) -> passes stay aligned
// without a grid barrier; each pass's 3.2 MB partition is L2-resident.
// R9 post-mortem: reported VGPR_Count tracks the ARCH half of the unified
// file (MFMA accs live in the AGPR half); (256,2) -> arch cap 128. PF=6's
// 96-reg ring + ~30 misc busted it -> 200 MB scratch. PF=4: 64-reg ring,
// ~94 arch total, 34 headroom. Uniform vmcnt(12) (R5-proven).

#define MFMA4(S, CT)                                                            \
    acc00[CT] = __builtin_amdgcn_mfma_f32_16x16x32_bf16(a0b[S], b0b[S], acc00[CT], 0, 0, 0); \
    acc01[CT] = __builtin_amdgcn_mfma_f32_16x16x32_bf16(a0b[S], b1b[S], acc01[CT], 0, 0, 0); \
    acc10[CT] = __builtin_amdgcn_mfma_f32_16x16x32_bf16(a1b[S], b0b[S], acc10[CT], 0, 0, 0); \
    acc11[CT] = __builtin_amdgcn_mfma_f32_16x16x32_bf16(a1b[S], b1b[S], acc11[CT], 0, 0, 0);

#define STAGE(J)                                                                \
    {                                                                           \
        asm volatile("s_waitcnt vmcnt(12)" ::: "memory");                       \
        __builtin_amdgcn_sched_barrier(0);                                      \
        constexpr int s_  = (J) % PF;                                           \
        constexpr int ct_ = (J) / KDIM;            /* consume tile for acc */   \
        MFMA4(s_, ct_)                                                          \
        {                                                                       \
            constexpr int T_  = (J) + PF;          /* issue target stage  */    \
            constexpr int kT_ = T_ % KDIM;                                      \
            const int lo_ = (T_ < SEGS) ? lo_cur : lo_next;                     \
            int raw0_ = rp0[(J) % 3];                                           \
            int raw1_ = rp1[(J) % 3];                                           \
            unsigned u0_ = ((unsigned)raw0_ - (unsigned)lo_ < (unsigned)PSIZE)  \
                               ? (unsigned)raw0_ : (unsigned)N_NODES;           \
            unsigned u1_ = ((unsigned)raw1_ - (unsigned)lo_ < (unsigned)PSIZE)  \
                               ? (unsigned)raw1_ : (unsigned)N_NODES;           \
            load_frag16(a0b[s_], dch + ((size_t)u0_ << 5));                     \
            load_frag16(a1b[s_], dch + ((size_t)u1_ << 5));                     \
            load_frag16(b0b[s_], wlane + kT_ * 1024);                           \
            load_frag16(b1b[s_], wlane + kT_ * 1024 + 512);                     \
        }                                                                       \
        {                                                                       \
            constexpr int T2_ = ((J) + 6) % SEGS;  /* idx for stage J+2 use */  \
            constexpr int t2_ = T2_ / KDIM, k2_ = T2_ % KDIM;                   \
            rp0[((J) + 2) % 3] = nlds[t2_ * 3456 + rA0 + k2_];                  \
            rp1[((J) + 2) % 3] = nlds[t2_ * 3456 + rA0 + 432 + k2_];            \
        }                                                                       \
    }

#define S9(a) STAGE(a) STAGE((a)+1) STAGE((a)+2) STAGE((a)+3) STAGE((a)+4) \
              STAGE((a)+5) STAGE((a)+6) STAGE((a)+7) STAGE((a)+8)

#define PRIME(T)                                                                \
    {                                                                           \
        int q0 = nlds[rA0 + (T)];                                               \
        int q1 = nlds[rA0 + 432 + (T)];                                         \
        unsigned u0_ = ((unsigned)q0 < (unsigned)PSIZE) ? (unsigned)q0          \
                                                        : (unsigned)N_NODES;    \
        unsigned u1_ = ((unsigned)q1 < (unsigned)PSIZE) ? (unsigned)q1          \
                                                        : (unsigned)N_NODES;    \
        load_frag16(a0b[(T)], dch + ((size_t)u0_ << 5));                        \
        load_frag16(a1b[(T)], dch + ((size_t)u1_ << 5));                        \
        load_frag16(b0b[(T)], wlane + (T) * 1024);                              \
        load_frag16(b1b[(T)], wlane + (T) * 1024 + 512);                        \
    }

__global__ __launch_bounds__(256, 2) void octconv_main_kernel(
    const int* __restrict__ neigh, const __bf16* __restrict__ data_bf,
    const __bf16* __restrict__ wpack, float* __restrict__ out) {
    __shared__ int nlds[TILES * 128 * KDIM];   // 55296 B: 4 tile slabs

    const int tid  = threadIdx.x;
    const int wave = tid >> 6;
    const int lane = tid & 63;
    const int r16  = lane & 15;
    const int half = lane >> 4;
    const int cb   = half << 3;

    // stage this block's 4 tiles' neigh -> LDS once (contiguous, coalesced)
    {
        const long long gbase = (long long)blockIdx.x * (TILES * 128 * KDIM);
        const long long gmax  = (long long)N_NODES * KDIM;
#pragma unroll 1
        for (int i = tid; i < TILES * 128 * KDIM; i += 256) {
            long long gg = gbase + i;
            nlds[i] = (gg < gmax) ? __builtin_nontemporal_load(&neigh[gg]) : -1;
        }
    }
    __syncthreads();

    const int rA0 = (wave * 32 + r16) * KDIM;    // row base within a tile slab
    const __bf16* dch   = data_bf + cb;
    const __bf16* wlane = wpack + (size_t)lane * 8;

    floatx4 acc00[TILES], acc01[TILES], acc10[TILES], acc11[TILES];
#pragma unroll
    for (int t = 0; t < TILES; ++t) {
        acc00[t] = floatx4{0.f, 0.f, 0.f, 0.f};
        acc01[t] = floatx4{0.f, 0.f, 0.f, 0.f};
        acc10[t] = floatx4{0.f, 0.f, 0.f, 0.f};
        acc11[t] = floatx4{0.f, 0.f, 0.f, 0.f};
    }

    bf16x8 a0b[PF], a1b[PF], b0b[PF], b1b[PF];   // asm-pinned frag ring
    int rp0[3], rp1[3];                          // idx ring, 2-stage lead

    // prologue (pass 0, lo=0): issue targets 0..3 (tile 0), prime idx ring
    PRIME(0) PRIME(1) PRIME(2) PRIME(3)
    rp0[0] = nlds[rA0 + 4]; rp1[0] = nlds[rA0 + 432 + 4];   // for target 4
    rp0[1] = nlds[rA0 + 5]; rp1[1] = nlds[rA0 + 432 + 5];   // for target 5

    int lo_cur = 0, lo_next = PSIZE;
#pragma unroll 1
    for (int p = 0; p < NPART; ++p) {
        S9(0)  S9(9)  S9(18) S9(27) S9(36) S9(45)
        S9(54) S9(63) S9(72) S9(81) S9(90) S9(99)
        lo_cur += PSIZE;
        lo_next += PSIZE;
    }

    asm volatile("s_waitcnt vmcnt(0)" ::: "memory");  // drain phantom issues
    __builtin_amdgcn_sched_barrier(0);

#pragma unroll
    for (int t = 0; t < TILES; ++t) {
        const int node_base = (blockIdx.x * TILES + t) * 128 + wave * 32;
#pragma unroll
        for (int r = 0; r < 4; ++r) {
            int n0 = node_base + half * 4 + r;
            int n1 = n0 + 16;
            if (n0 < N_NODES) {
                __builtin_nontemporal_store(acc00[t][r], &out[n0 * C_OUT + r16]);
                __builtin_nontemporal_store(acc01[t][r], &out[n0 * C_OUT + 16 + r16]);
            }
            if (n1 < N_NODES) {
                __builtin_nontemporal_store(acc10[t][r], &out[n1 * C_OUT + r16]);
                __builtin_nontemporal_store(acc11[t][r], &out[n1 * C_OUT + 16 + r16]);
            }
        }
    }
}

extern "C" void kernel_launch(void* const* d_in, const int* in_sizes, int n_in,
                              void* d_out, int out_size, void* d_ws, size_t ws_size,
                              hipStream_t stream) {
    const float* data    = (const float*)d_in[0];   // [N, C_IN] fp32
    const float* weights = (const float*)d_in[1];   // [K, C_IN, C_OUT] fp32
    const int*   neigh   = (const int*)d_in[2];     // [N, K] int32
    float*       out     = (float*)d_out;           // [N, C_OUT] fp32

    __bf16* data_bf = (__bf16*)d_ws;
    __bf16* wpack   = (__bf16*)((char*)d_ws + (size_t)(N_NODES + 1) * C_IN * sizeof(__bf16));

    // 1) fused convert + sentinel + weight pack
    hipLaunchKernelGGL(prep_kernel, dim3(3125 + 108), dim3(256), 0, stream,
                       data, weights, data_bf, wpack);

    // 2) persistent soft-synced partitioned gather-GEMM: 512 blocks (2/CU,
    //    fully co-resident, regular launch)
    hipLaunchKernelGGL(octconv_main_kernel, dim3(512), dim3(256), 0, stream,
                       neigh, data_bf, wpack, out);
}